// Round 1
// baseline (503.867 us; speedup 1.0000x reference)
//
#include <hip/hip_runtime.h>

// GAT layer, N=8192, F_IN=512, F_OUT=256. ALL tensors f32; adj int32.
// out = softmax_row(mask(leaky(s1_i+s2_j))) @ h, h = X@W, s{1,2} = h_f32@a{1,2}.
//
// R10 -> R11:
//  * Theory: attn was bound by hTt B-fragment refetch (256 blocks x 4 MB = 1.07 GB;
//    per-XCD working set == 4 MB == L2 size -> thrash to Infinity Cache).
//  * attn now AROWS=64 with 2-way column split (128 cols/block): B traffic halves
//    to 537 MB; ch = blockIdx&1 matches the round-robin XCD mapping so each XCD
//    streams ONE 2 MB hTt column-half -> L2-resident.
//  * P-generation duplicated across the column pair (same rows): +exp work x2,
//    fully overlapped VALU; numerics identical (same fragment k-order).

typedef __attribute__((ext_vector_type(8))) short bf16x8;
typedef __attribute__((ext_vector_type(4))) float fx4;
typedef __attribute__((ext_vector_type(4))) int ix4;
typedef __attribute__((ext_vector_type(2))) unsigned int ux2;

#define NN 8192
#define FIN 512
#define FOUT 256
#define PS 136     // LDS P row stride (shorts); 272B stride rotates banks (68 mod 32 = 4)
#define AROWS 64   // attn rows per block (column-split x2 keeps grid at 256)

__device__ __forceinline__ unsigned short f2bf(float f) {
    unsigned int x = __float_as_uint(f);
    x += 0x7fffu + ((x >> 16) & 1u);
    return (unsigned short)(x >> 16);
}
__device__ __forceinline__ bf16x8 pack8(fx4 a, fx4 b) {
    bf16x8 r;
    r[0] = (short)f2bf(a[0]); r[1] = (short)f2bf(a[1]);
    r[2] = (short)f2bf(a[2]); r[3] = (short)f2bf(a[3]);
    r[4] = (short)f2bf(b[0]); r[5] = (short)f2bf(b[1]);
    r[6] = (short)f2bf(b[2]); r[7] = (short)f2bf(b[3]);
    return r;
}

// ---------- kernel 0: WTt[((k>>5)*256+c)*32 + (k&31)] = bf16(W[k][c]) ----------
__global__ void wt_kernel(const float* __restrict__ W,
                          unsigned short* __restrict__ WTt) {
    const int c = threadIdx.x;
    const int k = blockIdx.x;
    WTt[((size_t)(k >> 5) * 256 + c) * 32 + (k & 31)] = f2bf(W[k * FOUT + c]);
}

// ---------- kernel 1 (merged): h-tile role + adj->mask streaming role ----------
// Blocks 0..511: 16-row h tile (MFMA) + fused s1/s2. Blocks 512..8703: pack
// adj (64M int32) into 1-bit mask (8 MB), 8 independent ix4 loads/thread.
// MFMA 16x16x32: A[m=l&15][k=q*8+j], B[k=q*8+j][n=l&15], D: col=l&15, row=q*4+r.
__global__ __launch_bounds__(256) void prep_kernel(
    const float* __restrict__ X,              // 8192x512 f32
    const unsigned short* __restrict__ WTt,   // tiled 256x512 bf16
    const float* __restrict__ A,              // 512 f32 (a1|a2)
    const int* __restrict__ adj,              // 8192x8192 i32
    unsigned short* __restrict__ hTt,         // tiled 256x8192 bf16
    float* __restrict__ s1, float* __restrict__ s2,
    unsigned int* __restrict__ mask)          // 8192x256 dwords
{
    __shared__ float s1sh[4][16], s2sh[4][16];
    const int tid = threadIdx.x;

    if (blockIdx.x >= 512) {
        // ---- mask role ----
        const int g = (blockIdx.x - 512) * 256 + tid;   // 0..2M-1
        const int* base = adj + (size_t)g * 32;
        ix4 v[8];
#pragma unroll
        for (int k = 0; k < 8; ++k) v[k] = *(const ix4*)(base + k * 4);
        unsigned int m = 0;
#pragma unroll
        for (int k = 0; k < 8; ++k)
#pragma unroll
            for (int j = 0; j < 4; ++j)
                m |= (v[k][j] != 0 ? 1u : 0u) << (k * 4 + j);
        mask[g] = m;
        return;
    }

    // ---- h role ----
    const int w = tid >> 6, l = tid & 63, q = l >> 4, lr = l & 15;
    const int r0 = blockIdx.x * 16;
    const int cbase = w * 64;
    fx4 acc[4] = {};

    for (int kb = 0; kb < FIN; kb += 32) {
        const float* xp = X + (size_t)(r0 + lr) * FIN + kb + q * 8;
        bf16x8 a0 = pack8(*(const fx4*)xp, *(const fx4*)(xp + 4));
#pragma unroll
        for (int tc = 0; tc < 4; ++tc) {
            bf16x8 b = *(const bf16x8*)(WTt + ((size_t)(kb >> 5) * 256 + cbase + tc * 16 + lr) * 32 + q * 8);
            acc[tc] = __builtin_amdgcn_mfma_f32_16x16x32_bf16(a0, b, acc[tc], 0, 0, 0);
        }
    }

    // tiled hTt write
    const int jb = r0 >> 5, jo = (r0 & 31) + q * 4;
#pragma unroll
    for (int tc = 0; tc < 4; ++tc) {
        const int c = cbase + tc * 16 + lr;
        ux2 hp;
        hp.x = (unsigned)f2bf(acc[tc][0]) | ((unsigned)f2bf(acc[tc][1]) << 16);
        hp.y = (unsigned)f2bf(acc[tc][2]) | ((unsigned)f2bf(acc[tc][3]) << 16);
        *(ux2*)(hTt + ((size_t)jb * 256 + c) * 32 + jo) = hp;
    }

    // fused s1/s2 from f32 accumulators
    float p1[4] = {}, p2[4] = {};
#pragma unroll
    for (int tc = 0; tc < 4; ++tc) {
        const int c = cbase + tc * 16 + lr;
        const float a1v = A[c], a2v = A[FOUT + c];
#pragma unroll
        for (int r = 0; r < 4; ++r) {
            p1[r] += acc[tc][r] * a1v;
            p2[r] += acc[tc][r] * a2v;
        }
    }
#pragma unroll
    for (int r = 0; r < 4; ++r) {
#pragma unroll
        for (int off = 1; off < 16; off <<= 1) {
            p1[r] += __shfl_xor(p1[r], off);
            p2[r] += __shfl_xor(p2[r], off);
        }
        if (lr == 0) { s1sh[w][q * 4 + r] = p1[r]; s2sh[w][q * 4 + r] = p2[r]; }
    }
    __syncthreads();
    if (tid < 16) {
        s1[r0 + tid] = s1sh[0][tid] + s1sh[1][tid] + s1sh[2][tid] + s1sh[3][tid];
        s2[r0 + tid] = s2sh[0][tid] + s2sh[1][tid] + s2sh[2][tid] + s2sh[3][tid];
    }
}

// ---------- kernel 2: fused masked-softmax @ h, f32 out ----------
// Grid 256 x 512 thr. 64 rows x 128 cols per block (2-way column split).
// ch = blockIdx&1 == XCD parity (round-robin mapping) -> each XCD's resident
// blocks stream the SAME 2 MB hTt column-half -> L2-resident B fragments.
// Pipelines: B-frags (hTt) 1 iter ahead (in flight across the barrier),
// mask/s2 2 iters ahead; P (64x128 bf16) double-buffered in LDS.
__global__ __launch_bounds__(512) void attn_kernel(
    const unsigned int* __restrict__ mask,   // 8192 x 256 dwords
    const unsigned short* __restrict__ hTt,  // tiled 256 x 8192 bf16
    const float* __restrict__ s1,
    const float* __restrict__ s2,
    float* __restrict__ out)                 // 8192 x 256 f32
{
    __shared__ unsigned short P[2][AROWS * PS];   // 34.8 KB
    __shared__ float dsh[AROWS];

    const int tid = threadIdx.x;
    const int rg = blockIdx.x >> 1;
    const int ch = blockIdx.x & 1;           // column half (matches XCD parity)
    const int r0 = rg * AROWS;
    const int c0 = ch * 128;

    // P-generation role: thread -> (row, 16-col group); P shared by both halves
    const int prow = tid >> 3;               // 0..63
    const int pq8 = tid & 7;                 // cols pq8*16..+15
    const float s1v = s1[r0 + prow];
    const unsigned int* mrow = mask + (size_t)(r0 + prow) * 256;
    const int mdw = pq8 >> 1;
    const int mshift = (pq8 & 1) * 16;
    float denp = 0.f;

    // MFMA role: 8 waves = 2 rowgroups x 4 colgroups; wave = 32 rows x 32 cols
    const int w = tid >> 6, l = tid & 63, q = l >> 4, lr = l & 15;
    const int wr = (w >> 2) * 32;            // row offset within the 64-row tile
    const int cbase = c0 + (w & 3) * 32;     // global col base of this wave
    fx4 acc[2][2] = {};

    struct LSet { unsigned int mval; fx4 s2v[4]; };
    LSet LA, LB;
    bf16x8 B0[4][2], B1[4][2];

    auto loadP = [&](int kt, LSet& L) {
        L.mval = mrow[kt * 4 + mdw];
        const float* s2p = s2 + kt * 128 + pq8 * 16;
#pragma unroll
        for (int j = 0; j < 4; ++j) L.s2v[j] = *(const fx4*)(s2p + j * 4);
    };
    auto calcP = [&](int b, const LSet& L) {
        const unsigned int m16 = (L.mval >> mshift) & 0xFFFFu;
        bf16x8 pv0, pv1;
#pragma unroll
        for (int j = 0; j < 16; ++j) {
            const float t = s1v + L.s2v[j >> 2][j & 3];
            float e = fmaxf(t, 0.2f * t);    // leaky_relu, alpha=0.2
            e = fminf(e, 30.f);              // overflow guard (inactive)
            const float p = ((m16 >> j) & 1u) ? __expf(e) : 0.f;
            denp += p;
            if (j < 8) pv0[j] = (short)f2bf(p);
            else       pv1[j - 8] = (short)f2bf(p);
        }
        unsigned short* dst = &P[b][prow * PS + pq8 * 16];
        *(bf16x8*)dst = pv0;                 // 2x 16B stores, ~2-way banks (free)
        *(bf16x8*)(dst + 8) = pv1;
    };
    auto loadB = [&](int it, bf16x8 (&B)[4][2]) {
#pragma unroll
        for (int ks = 0; ks < 4; ++ks)
#pragma unroll
            for (int tc = 0; tc < 2; ++tc)
                B[ks][tc] = *(const bf16x8*)(hTt + ((size_t)(it * 4 + ks) * 256 + cbase + tc * 16 + lr) * 32 + q * 8);
    };

    const int ITERS = NN / 128;   // 64
    loadP(0, LA);
    calcP(0, LA);
    loadP(1, LA);
    loadB(0, B0);
    __syncthreads();

    auto body = [&](int it, bf16x8 (&Bc)[4][2], bf16x8 (&Bn)[4][2],
                    LSet& Lc, LSet& Ln) {
        if (it + 1 < ITERS) loadB(it + 1, Bn);     // in flight across barrier
        if (it + 2 < ITERS) loadP(it + 2, Ln);     // 2-deep (HBM mask stream)
        const unsigned short* Pb = P[it & 1];
        bf16x8 af0[4], af1[4];
#pragma unroll
        for (int ks = 0; ks < 4; ++ks) {
            af0[ks] = *(const bf16x8*)(Pb + (wr + lr) * PS + ks * 32 + q * 8);
            af1[ks] = *(const bf16x8*)(Pb + (wr + 16 + lr) * PS + ks * 32 + q * 8);
        }
#pragma unroll
        for (int ks = 0; ks < 4; ++ks)
#pragma unroll
            for (int tc = 0; tc < 2; ++tc) {
                acc[0][tc] = __builtin_amdgcn_mfma_f32_16x16x32_bf16(af0[ks], Bc[ks][tc], acc[0][tc], 0, 0, 0);
                acc[1][tc] = __builtin_amdgcn_mfma_f32_16x16x32_bf16(af1[ks], Bc[ks][tc], acc[1][tc], 0, 0, 0);
            }
        if (it + 1 < ITERS) calcP((it + 1) & 1, Lc);
        __syncthreads();
    };

    for (int it = 0; it < ITERS; it += 2) {
        body(it, B0, B1, LA, LB);
        body(it + 1, B1, B0, LB, LA);
    }

    // den: reduce over the 8 lanes sharing a row (consecutive lanes)
    float v = denp;
    v += __shfl_xor(v, 1);
    v += __shfl_xor(v, 2);
    v += __shfl_xor(v, 4);
    if (pq8 == 0) dsh[prow] = v;
    __syncthreads();

#pragma unroll
    for (int mg = 0; mg < 2; ++mg) {
#pragma unroll
        for (int r = 0; r < 4; ++r) {
            const int row = wr + mg * 16 + q * 4 + r;
            const float dinv = 1.0f / fmaxf(dsh[row], 1e-30f);
#pragma unroll
            for (int tc = 0; tc < 2; ++tc) {
                out[(size_t)(r0 + row) * FOUT + cbase + tc * 16 + lr] = acc[mg][tc][r] * dinv;
            }
        }
    }
}

extern "C" void kernel_launch(void* const* d_in, const int* in_sizes, int n_in,
                              void* d_out, int out_size, void* d_ws, size_t ws_size,
                              hipStream_t stream) {
    const float *X = nullptr, *W = nullptr, *A = nullptr;
    const int* adj = nullptr;
    for (int i = 0; i < n_in; ++i) {
        switch (in_sizes[i]) {
            case NN * FIN:   X = (const float*)d_in[i]; break;
            case FIN * FOUT: W = (const float*)d_in[i]; break;
            case 2 * FOUT:   A = (const float*)d_in[i]; break;
            case NN * NN:    adj = (const int*)d_in[i]; break;
        }
    }
    if (!X) X = (const float*)d_in[0];
    if (!W) W = (const float*)d_in[1];
    if (!A) A = (const float*)d_in[2];
    if (!adj) adj = (const int*)d_in[3];
    float* out = (float*)d_out;

    // ws layout (13.25 MB of the 1 GiB ws; fill evidence r9):
    char* ws = (char*)d_ws;
    float* s1 = (float*)ws;                                 // 32 KB
    float* s2 = (float*)(ws + 32768);                       // 32 KB
    unsigned short* WTt = (unsigned short*)(ws + 98304);    // 256 KB
    unsigned short* hTt = (unsigned short*)(ws + 360448);   // 4 MB
    unsigned int* mask = (unsigned int*)(ws + 5242880);     // 8 MB

    wt_kernel<<<512, 256, 0, stream>>>(W, WTt);
    prep_kernel<<<512 + 8192, 256, 0, stream>>>(X, WTt, A, adj, hTt, s1, s2, mask);
    attn_kernel<<<(NN / AROWS) * 2, 512, 0, stream>>>(mask, hTt, s1, s2, out);
}

// Round 2
// 471.698 us; speedup vs baseline: 1.0682x; 1.0682x over previous
//
#include <hip/hip_runtime.h>

// GAT layer, N=8192, F_IN=512, F_OUT=256. ALL tensors f32; adj int32.
// out = softmax_row(mask(leaky(s1_i+s2_j))) @ h, h = X@W, s{1,2} = h_f32@a{1,2}.
//
// R11 -> R12:
//  * R11 (column-split) regressed +37us -> full revert to the 467us R10 structure.
//    Lesson: hTt refetch is L2-served (32 blocks/XCD stream the same 4MB in the
//    same order); traffic was never the attn bottleneck.
//  * New lever: R10's in-loop __syncthreads() emits s_waitcnt vmcnt(0) before
//    s_barrier -> drains the 1-ahead B prefetch AND the 2-ahead mask prefetch
//    every iteration (mask is HBM, ~900cyc). Replace with lgkmcnt(0)-only drain
//    + raw s_barrier: LDS P-buffer handoff stays correct, global loads stay in
//    flight across the barrier (consumers get compiler vmcnt(N) waits).
//  * s_setprio(1) around the MFMA cluster (T5; measured +4-7% on attn shapes).

typedef __attribute__((ext_vector_type(8))) short bf16x8;
typedef __attribute__((ext_vector_type(4))) float fx4;
typedef __attribute__((ext_vector_type(4))) int ix4;
typedef __attribute__((ext_vector_type(2))) unsigned int ux2;

#define NN 8192
#define FIN 512
#define FOUT 256
#define PS 136     // LDS P row stride (shorts); 272B stride -> (lr+q) rotation, conflict-free b128
#define AROWS 32   // attn rows per block

__device__ __forceinline__ unsigned short f2bf(float f) {
    unsigned int x = __float_as_uint(f);
    x += 0x7fffu + ((x >> 16) & 1u);
    return (unsigned short)(x >> 16);
}
__device__ __forceinline__ bf16x8 pack8(fx4 a, fx4 b) {
    bf16x8 r;
    r[0] = (short)f2bf(a[0]); r[1] = (short)f2bf(a[1]);
    r[2] = (short)f2bf(a[2]); r[3] = (short)f2bf(a[3]);
    r[4] = (short)f2bf(b[0]); r[5] = (short)f2bf(b[1]);
    r[6] = (short)f2bf(b[2]); r[7] = (short)f2bf(b[3]);
    return r;
}

// ---------- kernel 0: WTt[((k>>5)*256+c)*32 + (k&31)] = bf16(W[k][c]) ----------
__global__ void wt_kernel(const float* __restrict__ W,
                          unsigned short* __restrict__ WTt) {
    const int c = threadIdx.x;
    const int k = blockIdx.x;
    WTt[((size_t)(k >> 5) * 256 + c) * 32 + (k & 31)] = f2bf(W[k * FOUT + c]);
}

// ---------- kernel 1 (merged): h-tile role + adj->mask streaming role ----------
// Blocks 0..511: 16-row h tile (MFMA) + fused s1/s2. Blocks 512..8703: pack
// adj (64M int32) into 1-bit mask (8 MB), 8 independent ix4 loads/thread.
// MFMA 16x16x32: A[m=l&15][k=q*8+j], B[k=q*8+j][n=l&15], D: col=l&15, row=q*4+r.
__global__ __launch_bounds__(256) void prep_kernel(
    const float* __restrict__ X,              // 8192x512 f32
    const unsigned short* __restrict__ WTt,   // tiled 256x512 bf16
    const float* __restrict__ A,              // 512 f32 (a1|a2)
    const int* __restrict__ adj,              // 8192x8192 i32
    unsigned short* __restrict__ hTt,         // tiled 256x8192 bf16
    float* __restrict__ s1, float* __restrict__ s2,
    unsigned int* __restrict__ mask)          // 8192x256 dwords
{
    __shared__ float s1sh[4][16], s2sh[4][16];
    const int tid = threadIdx.x;

    if (blockIdx.x >= 512) {
        // ---- mask role ----
        const int g = (blockIdx.x - 512) * 256 + tid;   // 0..2M-1
        const int* base = adj + (size_t)g * 32;
        ix4 v[8];
#pragma unroll
        for (int k = 0; k < 8; ++k) v[k] = *(const ix4*)(base + k * 4);
        unsigned int m = 0;
#pragma unroll
        for (int k = 0; k < 8; ++k)
#pragma unroll
            for (int j = 0; j < 4; ++j)
                m |= (v[k][j] != 0 ? 1u : 0u) << (k * 4 + j);
        mask[g] = m;
        return;
    }

    // ---- h role ----
    const int w = tid >> 6, l = tid & 63, q = l >> 4, lr = l & 15;
    const int r0 = blockIdx.x * 16;
    const int cbase = w * 64;
    fx4 acc[4] = {};

    for (int kb = 0; kb < FIN; kb += 32) {
        const float* xp = X + (size_t)(r0 + lr) * FIN + kb + q * 8;
        bf16x8 a0 = pack8(*(const fx4*)xp, *(const fx4*)(xp + 4));
#pragma unroll
        for (int tc = 0; tc < 4; ++tc) {
            bf16x8 b = *(const bf16x8*)(WTt + ((size_t)(kb >> 5) * 256 + cbase + tc * 16 + lr) * 32 + q * 8);
            acc[tc] = __builtin_amdgcn_mfma_f32_16x16x32_bf16(a0, b, acc[tc], 0, 0, 0);
        }
    }

    // tiled hTt write
    const int jb = r0 >> 5, jo = (r0 & 31) + q * 4;
#pragma unroll
    for (int tc = 0; tc < 4; ++tc) {
        const int c = cbase + tc * 16 + lr;
        ux2 hp;
        hp.x = (unsigned)f2bf(acc[tc][0]) | ((unsigned)f2bf(acc[tc][1]) << 16);
        hp.y = (unsigned)f2bf(acc[tc][2]) | ((unsigned)f2bf(acc[tc][3]) << 16);
        *(ux2*)(hTt + ((size_t)jb * 256 + c) * 32 + jo) = hp;
    }

    // fused s1/s2 from f32 accumulators
    float p1[4] = {}, p2[4] = {};
#pragma unroll
    for (int tc = 0; tc < 4; ++tc) {
        const int c = cbase + tc * 16 + lr;
        const float a1v = A[c], a2v = A[FOUT + c];
#pragma unroll
        for (int r = 0; r < 4; ++r) {
            p1[r] += acc[tc][r] * a1v;
            p2[r] += acc[tc][r] * a2v;
        }
    }
#pragma unroll
    for (int r = 0; r < 4; ++r) {
#pragma unroll
        for (int off = 1; off < 16; off <<= 1) {
            p1[r] += __shfl_xor(p1[r], off);
            p2[r] += __shfl_xor(p2[r], off);
        }
        if (lr == 0) { s1sh[w][q * 4 + r] = p1[r]; s2sh[w][q * 4 + r] = p2[r]; }
    }
    __syncthreads();
    if (tid < 16) {
        s1[r0 + tid] = s1sh[0][tid] + s1sh[1][tid] + s1sh[2][tid] + s1sh[3][tid];
        s2[r0 + tid] = s2sh[0][tid] + s2sh[1][tid] + s2sh[2][tid] + s2sh[3][tid];
    }
}

// ---------- kernel 2: fused masked-softmax @ h, f32 out ----------
// Grid 256 x 512 thr. 32 rows/block; wave w owns cols w*32..+31.
// Pipelines: B-frags (hTt) 1 iter ahead, mask/s2 2 iters ahead; P (32x128 bf16)
// double-buffered in LDS. In-loop barrier drains ONLY lgkmcnt (LDS handoff);
// global prefetches stay in flight across s_barrier (consumers get vmcnt(N)).
__global__ __launch_bounds__(512) void attn_kernel(
    const unsigned int* __restrict__ mask,   // 8192 x 256 dwords
    const unsigned short* __restrict__ hTt,  // tiled 256 x 8192 bf16
    const float* __restrict__ s1,
    const float* __restrict__ s2,
    float* __restrict__ out)                 // 8192 x 256 f32
{
    __shared__ unsigned short P[2][AROWS * PS];   // 17.4 KB
    __shared__ float dsh[AROWS];

    const int tid = threadIdx.x;
    const int r0 = blockIdx.x * AROWS;

    // P-generation role: thread -> (row, 8-col group)
    const int prow = tid >> 4;                 // 0..31
    const int pq = tid & 15;                   // cols pq*8..+7
    const float s1v = s1[r0 + prow];
    const unsigned int* mrow = mask + (size_t)(r0 + prow) * 256;
    const int mshift = (pq & 3) * 8;
    float denp = 0.f;

    // MFMA role
    const int w = tid >> 6, l = tid & 63, q = l >> 4, lr = l & 15;
    const int cbase = w * 32;
    fx4 acc[2][2] = {};

    struct LSet { unsigned int mval; fx4 s2a, s2b; };
    LSet LA, LB;
    bf16x8 B0[4][2], B1[4][2];

    auto loadP = [&](int kt, LSet& L) {
        L.mval = mrow[kt * 4 + (pq >> 2)];
        L.s2a = *(const fx4*)(s2 + kt * 128 + pq * 8);
        L.s2b = *(const fx4*)(s2 + kt * 128 + pq * 8 + 4);
    };
    auto calcP = [&](int b, const LSet& L) {
        const unsigned int mbyte = (L.mval >> mshift) & 0xFFu;
        bf16x8 pv;
#pragma unroll
        for (int j = 0; j < 8; ++j) {
            const float s2j = (j < 4) ? L.s2a[j] : L.s2b[j - 4];
            float t = s1v + s2j;
            float e = fmaxf(t, 0.2f * t);      // leaky_relu, alpha=0.2
            e = fminf(e, 30.f);                // overflow guard (inactive)
            const float p = ((mbyte >> j) & 1u) ? __expf(e) : 0.f;
            denp += p;
            pv[j] = (short)f2bf(p);
        }
        *(bf16x8*)(&P[b][prow * PS + pq * 8]) = pv;   // 16B store
    };
    auto loadB = [&](int it, bf16x8 (&B)[4][2]) {
#pragma unroll
        for (int ks = 0; ks < 4; ++ks)
#pragma unroll
            for (int tc = 0; tc < 2; ++tc)
                B[ks][tc] = *(const bf16x8*)(hTt + ((size_t)(it * 4 + ks) * 256 + cbase + tc * 16 + lr) * 32 + q * 8);
    };

    // LDS-only barrier: ds_writes drained (lgkmcnt), global loads stay in flight.
    auto ldsBarrier = [&]() {
        asm volatile("s_waitcnt lgkmcnt(0)" ::: "memory");
        __builtin_amdgcn_s_barrier();
    };

    const int ITERS = NN / 128;   // 64
    loadP(0, LA);
    calcP(0, LA);
    loadP(1, LA);
    loadB(0, B0);
    ldsBarrier();

    auto body = [&](int it, bf16x8 (&Bc)[4][2], bf16x8 (&Bn)[4][2],
                    LSet& Lc, LSet& Ln) {
        if (it + 1 < ITERS) loadB(it + 1, Bn);     // in flight across barrier
        if (it + 2 < ITERS) loadP(it + 2, Ln);     // 2-deep (HBM mask stream)
        const unsigned short* Pb = P[it & 1];
        bf16x8 af0[4], af1[4];
#pragma unroll
        for (int ks = 0; ks < 4; ++ks) {
            af0[ks] = *(const bf16x8*)(Pb + lr * PS + ks * 32 + q * 8);
            af1[ks] = *(const bf16x8*)(Pb + (16 + lr) * PS + ks * 32 + q * 8);
        }
        __builtin_amdgcn_s_setprio(1);
#pragma unroll
        for (int ks = 0; ks < 4; ++ks)
#pragma unroll
            for (int tc = 0; tc < 2; ++tc) {
                acc[0][tc] = __builtin_amdgcn_mfma_f32_16x16x32_bf16(af0[ks], Bc[ks][tc], acc[0][tc], 0, 0, 0);
                acc[1][tc] = __builtin_amdgcn_mfma_f32_16x16x32_bf16(af1[ks], Bc[ks][tc], acc[1][tc], 0, 0, 0);
            }
        __builtin_amdgcn_s_setprio(0);
        if (it + 1 < ITERS) calcP((it + 1) & 1, Lc);
        ldsBarrier();
    };

    for (int it = 0; it < ITERS; it += 2) {
        body(it, B0, B1, LA, LB);
        body(it + 1, B1, B0, LB, LA);
    }

    // den: reduce over the 16 lanes sharing a row
    float v = denp;
    v += __shfl_xor(v, 1);
    v += __shfl_xor(v, 2);
    v += __shfl_xor(v, 4);
    v += __shfl_xor(v, 8);
    if (pq == 0) dsh[prow] = v;
    __syncthreads();

#pragma unroll
    for (int mg = 0; mg < 2; ++mg) {
#pragma unroll
        for (int r = 0; r < 4; ++r) {
            const int row = mg * 16 + q * 4 + r;
            const float dinv = 1.0f / fmaxf(dsh[row], 1e-30f);
#pragma unroll
            for (int tc = 0; tc < 2; ++tc) {
                out[(size_t)(r0 + row) * FOUT + cbase + tc * 16 + lr] = acc[mg][tc][r] * dinv;
            }
        }
    }
}

extern "C" void kernel_launch(void* const* d_in, const int* in_sizes, int n_in,
                              void* d_out, int out_size, void* d_ws, size_t ws_size,
                              hipStream_t stream) {
    const float *X = nullptr, *W = nullptr, *A = nullptr;
    const int* adj = nullptr;
    for (int i = 0; i < n_in; ++i) {
        switch (in_sizes[i]) {
            case NN * FIN:   X = (const float*)d_in[i]; break;
            case FIN * FOUT: W = (const float*)d_in[i]; break;
            case 2 * FOUT:   A = (const float*)d_in[i]; break;
            case NN * NN:    adj = (const int*)d_in[i]; break;
        }
    }
    if (!X) X = (const float*)d_in[0];
    if (!W) W = (const float*)d_in[1];
    if (!A) A = (const float*)d_in[2];
    if (!adj) adj = (const int*)d_in[3];
    float* out = (float*)d_out;

    // ws layout (13.25 MB of the 1 GiB ws; fill evidence r9):
    char* ws = (char*)d_ws;
    float* s1 = (float*)ws;                                 // 32 KB
    float* s2 = (float*)(ws + 32768);                       // 32 KB
    unsigned short* WTt = (unsigned short*)(ws + 98304);    // 256 KB
    unsigned short* hTt = (unsigned short*)(ws + 360448);   // 4 MB
    unsigned int* mask = (unsigned int*)(ws + 5242880);     // 8 MB

    wt_kernel<<<512, 256, 0, stream>>>(W, WTt);
    prep_kernel<<<512 + 8192, 256, 0, stream>>>(X, WTt, A, adj, hTt, s1, s2, mask);
    attn_kernel<<<NN / AROWS, 512, 0, stream>>>(mask, hTt, s1, s2, out);
}

// Round 3
// 442.418 us; speedup vs baseline: 1.1389x; 1.0662x over previous
//
#include <hip/hip_runtime.h>

// GAT layer, N=8192, F_IN=512, F_OUT=256. ALL tensors f32; adj int32.
// out = softmax_row(mask(leaky(s1_i+s2_j))) @ h, h = X@W, s{1,2} = h_f32@a{1,2}.
//
// R12 -> R13:
//  * R12 (lgkm-only barrier + setprio) was noise -> per-iter latency exposure
//    was not the bottleneck. Kept (harmless, and matters more now).
//  * STRUCTURAL: delete the adj->mask prep phase (268 MB HBM read, ~43us of
//    serial time). attn now streams its own 32-row slice of adj directly
//    (32 B/thread/iter, 2-iter-ahead prefetch), overlapping the HBM stream
//    with MFMA+softmax compute that previously left HBM idle.
//  * adj loads are NON-TEMPORAL (nt) so the 268 MB stream does not evict the
//    L2-resident 4 MB hTt working set (R11 lesson: hTt L2 residency matters).
//  * prep is now h-role only (512 blocks, ~10us, X-read bound).

typedef __attribute__((ext_vector_type(8))) short bf16x8;
typedef __attribute__((ext_vector_type(4))) float fx4;
typedef __attribute__((ext_vector_type(4))) int ix4;
typedef __attribute__((ext_vector_type(2))) unsigned int ux2;

#define NN 8192
#define FIN 512
#define FOUT 256
#define PS 136     // LDS P row stride (shorts); 272B stride -> conflict-free b128
#define AROWS 32   // attn rows per block

__device__ __forceinline__ unsigned short f2bf(float f) {
    unsigned int x = __float_as_uint(f);
    x += 0x7fffu + ((x >> 16) & 1u);
    return (unsigned short)(x >> 16);
}
__device__ __forceinline__ bf16x8 pack8(fx4 a, fx4 b) {
    bf16x8 r;
    r[0] = (short)f2bf(a[0]); r[1] = (short)f2bf(a[1]);
    r[2] = (short)f2bf(a[2]); r[3] = (short)f2bf(a[3]);
    r[4] = (short)f2bf(b[0]); r[5] = (short)f2bf(b[1]);
    r[6] = (short)f2bf(b[2]); r[7] = (short)f2bf(b[3]);
    return r;
}

// ---------- kernel 0: WTt[((k>>5)*256+c)*32 + (k&31)] = bf16(W[k][c]) ----------
__global__ void wt_kernel(const float* __restrict__ W,
                          unsigned short* __restrict__ WTt) {
    const int c = threadIdx.x;
    const int k = blockIdx.x;
    WTt[((size_t)(k >> 5) * 256 + c) * 32 + (k & 31)] = f2bf(W[k * FOUT + c]);
}

// ---------- kernel 1: h-tile (MFMA) + fused s1/s2 ----------
// 512 blocks x 16 rows. MFMA 16x16x32: A[m=l&15][k=q*8+j], B[k=q*8+j][n=l&15],
// D: col=l&15, row=q*4+r.
__global__ __launch_bounds__(256) void prep_kernel(
    const float* __restrict__ X,              // 8192x512 f32
    const unsigned short* __restrict__ WTt,   // tiled 256x512 bf16
    const float* __restrict__ A,              // 512 f32 (a1|a2)
    unsigned short* __restrict__ hTt,         // tiled 256x8192 bf16
    float* __restrict__ s1, float* __restrict__ s2)
{
    __shared__ float s1sh[4][16], s2sh[4][16];
    const int tid = threadIdx.x;

    const int w = tid >> 6, l = tid & 63, q = l >> 4, lr = l & 15;
    const int r0 = blockIdx.x * 16;
    const int cbase = w * 64;
    fx4 acc[4] = {};

    for (int kb = 0; kb < FIN; kb += 32) {
        const float* xp = X + (size_t)(r0 + lr) * FIN + kb + q * 8;
        bf16x8 a0 = pack8(*(const fx4*)xp, *(const fx4*)(xp + 4));
#pragma unroll
        for (int tc = 0; tc < 4; ++tc) {
            bf16x8 b = *(const bf16x8*)(WTt + ((size_t)(kb >> 5) * 256 + cbase + tc * 16 + lr) * 32 + q * 8);
            acc[tc] = __builtin_amdgcn_mfma_f32_16x16x32_bf16(a0, b, acc[tc], 0, 0, 0);
        }
    }

    // tiled hTt write
    const int jb = r0 >> 5, jo = (r0 & 31) + q * 4;
#pragma unroll
    for (int tc = 0; tc < 4; ++tc) {
        const int c = cbase + tc * 16 + lr;
        ux2 hp;
        hp.x = (unsigned)f2bf(acc[tc][0]) | ((unsigned)f2bf(acc[tc][1]) << 16);
        hp.y = (unsigned)f2bf(acc[tc][2]) | ((unsigned)f2bf(acc[tc][3]) << 16);
        *(ux2*)(hTt + ((size_t)jb * 256 + c) * 32 + jo) = hp;
    }

    // fused s1/s2 from f32 accumulators
    float p1[4] = {}, p2[4] = {};
#pragma unroll
    for (int tc = 0; tc < 4; ++tc) {
        const int c = cbase + tc * 16 + lr;
        const float a1v = A[c], a2v = A[FOUT + c];
#pragma unroll
        for (int r = 0; r < 4; ++r) {
            p1[r] += acc[tc][r] * a1v;
            p2[r] += acc[tc][r] * a2v;
        }
    }
#pragma unroll
    for (int r = 0; r < 4; ++r) {
#pragma unroll
        for (int off = 1; off < 16; off <<= 1) {
            p1[r] += __shfl_xor(p1[r], off);
            p2[r] += __shfl_xor(p2[r], off);
        }
        if (lr == 0) { s1sh[w][q * 4 + r] = p1[r]; s2sh[w][q * 4 + r] = p2[r]; }
    }
    __syncthreads();
    if (tid < 16) {
        s1[r0 + tid] = s1sh[0][tid] + s1sh[1][tid] + s1sh[2][tid] + s1sh[3][tid];
        s2[r0 + tid] = s2sh[0][tid] + s2sh[1][tid] + s2sh[2][tid] + s2sh[3][tid];
    }
}

// ---------- kernel 2: fused masked-softmax @ h, f32 out ----------
// Grid 256 x 512 thr. 32 rows/block; wave w owns cols w*32..+31.
// adj streamed DIRECTLY (nt loads, 32 B/thread/iter, 2 iters ahead) -> the
// 268 MB HBM stream hides under MFMA+softmax; no mask precompute pass.
// B-frags (hTt, L2-resident) 1 iter ahead; P (32x128 bf16) double-buffered in
// LDS; in-loop barrier drains ONLY lgkmcnt so global prefetches stay in flight.
__global__ __launch_bounds__(512) void attn_kernel(
    const int* __restrict__ adj,             // 8192 x 8192 i32
    const unsigned short* __restrict__ hTt,  // tiled 256 x 8192 bf16
    const float* __restrict__ s1,
    const float* __restrict__ s2,
    float* __restrict__ out)                 // 8192 x 256 f32
{
    __shared__ unsigned short P[2][AROWS * PS];   // 17.4 KB
    __shared__ float dsh[AROWS];

    const int tid = threadIdx.x;
    const int r0 = blockIdx.x * AROWS;

    // P-generation role: thread -> (row, 8-col group)
    const int prow = tid >> 4;                 // 0..31
    const int pq = tid & 15;                   // cols pq*8..+7
    const float s1v = s1[r0 + prow];
    const int* arow = adj + (size_t)(r0 + prow) * NN + pq * 8;
    float denp = 0.f;

    // MFMA role
    const int w = tid >> 6, l = tid & 63, q = l >> 4, lr = l & 15;
    const int cbase = w * 32;
    fx4 acc[2][2] = {};

    struct LSet { ix4 v0, v1; fx4 s2a, s2b; };
    LSet LA, LB;
    bf16x8 B0[4][2], B1[4][2];

    auto loadP = [&](int kt, LSet& L) {
        const int* ap = arow + kt * 128;
        L.v0 = __builtin_nontemporal_load((const ix4*)ap);       // nt: keep the
        L.v1 = __builtin_nontemporal_load((const ix4*)(ap + 4)); // stream out of L2
        L.s2a = *(const fx4*)(s2 + kt * 128 + pq * 8);
        L.s2b = *(const fx4*)(s2 + kt * 128 + pq * 8 + 4);
    };
    auto calcP = [&](int b, const LSet& L) {
        bf16x8 pv;
#pragma unroll
        for (int j = 0; j < 8; ++j) {
            const int aj = (j < 4) ? L.v0[j] : L.v1[j - 4];
            const float s2j = (j < 4) ? L.s2a[j] : L.s2b[j - 4];
            float t = s1v + s2j;
            float e = fmaxf(t, 0.2f * t);      // leaky_relu, alpha=0.2
            e = fminf(e, 30.f);                // overflow guard (inactive)
            const float p = (aj != 0) ? __expf(e) : 0.f;
            denp += p;
            pv[j] = (short)f2bf(p);
        }
        *(bf16x8*)(&P[b][prow * PS + pq * 8]) = pv;   // 16B store
    };
    auto loadB = [&](int it, bf16x8 (&B)[4][2]) {
#pragma unroll
        for (int ks = 0; ks < 4; ++ks)
#pragma unroll
            for (int tc = 0; tc < 2; ++tc)
                B[ks][tc] = *(const bf16x8*)(hTt + ((size_t)(it * 4 + ks) * 256 + cbase + tc * 16 + lr) * 32 + q * 8);
    };

    // LDS-only barrier: ds_writes drained (lgkmcnt), global loads stay in flight.
    auto ldsBarrier = [&]() {
        asm volatile("s_waitcnt lgkmcnt(0)" ::: "memory");
        __builtin_amdgcn_s_barrier();
    };

    const int ITERS = NN / 128;   // 64
    loadP(0, LA);
    calcP(0, LA);
    loadP(1, LA);
    loadB(0, B0);
    ldsBarrier();

    auto body = [&](int it, bf16x8 (&Bc)[4][2], bf16x8 (&Bn)[4][2],
                    LSet& Lc, LSet& Ln) {
        if (it + 1 < ITERS) loadB(it + 1, Bn);     // in flight across barrier
        if (it + 2 < ITERS) loadP(it + 2, Ln);     // 2-deep (HBM adj stream)
        const unsigned short* Pb = P[it & 1];
        bf16x8 af0[4], af1[4];
#pragma unroll
        for (int ks = 0; ks < 4; ++ks) {
            af0[ks] = *(const bf16x8*)(Pb + lr * PS + ks * 32 + q * 8);
            af1[ks] = *(const bf16x8*)(Pb + (16 + lr) * PS + ks * 32 + q * 8);
        }
        __builtin_amdgcn_s_setprio(1);
#pragma unroll
        for (int ks = 0; ks < 4; ++ks)
#pragma unroll
            for (int tc = 0; tc < 2; ++tc) {
                acc[0][tc] = __builtin_amdgcn_mfma_f32_16x16x32_bf16(af0[ks], Bc[ks][tc], acc[0][tc], 0, 0, 0);
                acc[1][tc] = __builtin_amdgcn_mfma_f32_16x16x32_bf16(af1[ks], Bc[ks][tc], acc[1][tc], 0, 0, 0);
            }
        __builtin_amdgcn_s_setprio(0);
        if (it + 1 < ITERS) calcP((it + 1) & 1, Lc);
        ldsBarrier();
    };

    for (int it = 0; it < ITERS; it += 2) {
        body(it, B0, B1, LA, LB);
        body(it + 1, B1, B0, LB, LA);
    }

    // den: reduce over the 16 lanes sharing a row
    float v = denp;
    v += __shfl_xor(v, 1);
    v += __shfl_xor(v, 2);
    v += __shfl_xor(v, 4);
    v += __shfl_xor(v, 8);
    if (pq == 0) dsh[prow] = v;
    __syncthreads();

#pragma unroll
    for (int mg = 0; mg < 2; ++mg) {
#pragma unroll
        for (int r = 0; r < 4; ++r) {
            const int row = mg * 16 + q * 4 + r;
            const float dinv = 1.0f / fmaxf(dsh[row], 1e-30f);
#pragma unroll
            for (int tc = 0; tc < 2; ++tc) {
                out[(size_t)(r0 + row) * FOUT + cbase + tc * 16 + lr] = acc[mg][tc][r] * dinv;
            }
        }
    }
}

extern "C" void kernel_launch(void* const* d_in, const int* in_sizes, int n_in,
                              void* d_out, int out_size, void* d_ws, size_t ws_size,
                              hipStream_t stream) {
    const float *X = nullptr, *W = nullptr, *A = nullptr;
    const int* adj = nullptr;
    for (int i = 0; i < n_in; ++i) {
        switch (in_sizes[i]) {
            case NN * FIN:   X = (const float*)d_in[i]; break;
            case FIN * FOUT: W = (const float*)d_in[i]; break;
            case 2 * FOUT:   A = (const float*)d_in[i]; break;
            case NN * NN:    adj = (const int*)d_in[i]; break;
        }
    }
    if (!X) X = (const float*)d_in[0];
    if (!W) W = (const float*)d_in[1];
    if (!A) A = (const float*)d_in[2];
    if (!adj) adj = (const int*)d_in[3];
    float* out = (float*)d_out;

    // ws layout (subset of the 1 GiB ws; mask slot retired in R13):
    char* ws = (char*)d_ws;
    float* s1 = (float*)ws;                                 // 32 KB
    float* s2 = (float*)(ws + 32768);                       // 32 KB
    unsigned short* WTt = (unsigned short*)(ws + 98304);    // 256 KB
    unsigned short* hTt = (unsigned short*)(ws + 360448);   // 4 MB

    wt_kernel<<<512, 256, 0, stream>>>(W, WTt);
    prep_kernel<<<512, 256, 0, stream>>>(X, WTt, A, hTt, s1, s2);
    attn_kernel<<<NN / AROWS, 512, 0, stream>>>(adj, hTt, s1, s2, out);
}